// Round 1
// baseline (502.785 us; speedup 1.0000x reference)
//
#include <hip/hip_runtime.h>
#include <hip/hip_bf16.h>

#define SEQ 512
#define EMB 256
#define NHEAD 8
#define HD 32

using bf16x8 = __attribute__((ext_vector_type(8))) short;
using f32x4  = __attribute__((ext_vector_type(4))) float;

static __device__ __forceinline__ unsigned short f2bf(float x) {
    union { float f; unsigned int u; } v; v.f = x;
    unsigned int r = v.u + 0x7FFFu + ((v.u >> 16) & 1u);
    return (unsigned short)(r >> 16);
}

// ---------------- prep: gather embeds, build masked-concat A (bf16) + query (bf16)
__global__ __launch_bounds__(256) void prep_kernel(
    const int* __restrict__ item_inputs,
    const int* __restrict__ label_inputs,
    const int* __restrict__ item_ids,
    const float* __restrict__ embeds,
    unsigned short* __restrict__ Abig,   // 16384 x 512 bf16
    unsigned short* __restrict__ qbf)    // 16384 x 256 bf16
{
    int t = threadIdx.x;
    int r = blockIdx.x * 2 + (t >> 7);
    int j = (t & 127) * 2;
    int item = item_inputs[r];
    int lab  = label_inputs[r];
    int qid  = item_ids[r];
    float2 e2 = *(const float2*)(embeds + (size_t)item * EMB + j);
    ushort2 on  = make_ushort2(f2bf(e2.x), f2bf(e2.y));
    ushort2 off = make_ushort2(0, 0);
    *(ushort2*)(Abig + (size_t)r * 512 + j)       = lab ? on : off;
    *(ushort2*)(Abig + (size_t)r * 512 + 256 + j) = lab ? off : on;
    float2 q2 = *(const float2*)(embeds + (size_t)qid * EMB + j);
    *(ushort2*)(qbf + (size_t)r * 256 + j) = make_ushort2(f2bf(q2.x), f2bf(q2.y));
}

// ---------------- weight transpose + bf16 convert: W (K x N) -> WT (N x K)
__global__ void wtrans_kernel(const float* __restrict__ W,
                              unsigned short* __restrict__ WT,
                              int K, int N)
{
    int idx = blockIdx.x * 256 + threadIdx.x;
    if (idx >= K * N) return;
    int n = idx / K, k = idx - n * K;
    WT[idx] = f2bf(W[(size_t)k * N + n]);
}

// ---------------- MFMA GEMM: C(M x 256) = A(M x KDIM) * WT^T + bias, opt relu
// block tile 64x128, 4 waves (2x2), wave tile 32x64
template<int KDIM, int RELU, int OUTBF>
__global__ __launch_bounds__(256, 2) void gemm_kernel(
    const unsigned short* __restrict__ A,
    const unsigned short* __restrict__ BT,   // 256 x KDIM (pre-transposed)
    const float* __restrict__ bias,
    void* __restrict__ Cout)
{
    __shared__ unsigned short As[64][40];    // pad 32->40 to break bank conflicts
    __shared__ unsigned short Bs[128][40];
    const int t = threadIdx.x;
    const int row0 = blockIdx.x * 64;
    const int col0 = blockIdx.y * 128;
    const int wid = t >> 6, lane = t & 63;
    const int wm = wid & 1, wn = wid >> 1;
    const int lg = lane >> 4, l15 = lane & 15;

    f32x4 acc[2][4];
    #pragma unroll
    for (int i = 0; i < 2; i++)
        #pragma unroll
        for (int j = 0; j < 4; j++) acc[i][j] = (f32x4){0.f, 0.f, 0.f, 0.f};

    const int arow = t >> 2, achk = t & 3;   // A: 64 rows x 4 x 16B
    const int brow = t >> 1, bhalf = t & 1;  // B: 128 rows x 2 x 32B

    for (int k0 = 0; k0 < KDIM; k0 += 32) {
        __syncthreads();
        *(uint4*)(&As[arow][achk * 8]) =
            *(const uint4*)(A + (size_t)(row0 + arow) * KDIM + k0 + achk * 8);
        const unsigned short* bsrc = BT + (size_t)(col0 + brow) * KDIM + k0 + bhalf * 16;
        *(uint4*)(&Bs[brow][bhalf * 16])     = *(const uint4*)(bsrc);
        *(uint4*)(&Bs[brow][bhalf * 16 + 8]) = *(const uint4*)(bsrc + 8);
        __syncthreads();
        bf16x8 af[2], bfr[4];
        #pragma unroll
        for (int fm = 0; fm < 2; fm++)
            af[fm] = *(const bf16x8*)(&As[wm * 32 + fm * 16 + l15][lg * 8]);
        #pragma unroll
        for (int fn = 0; fn < 4; fn++)
            bfr[fn] = *(const bf16x8*)(&Bs[wn * 64 + fn * 16 + l15][lg * 8]);
        #pragma unroll
        for (int fm = 0; fm < 2; fm++)
            #pragma unroll
            for (int fn = 0; fn < 4; fn++)
                acc[fm][fn] = __builtin_amdgcn_mfma_f32_16x16x32_bf16(
                    af[fm], bfr[fn], acc[fm][fn], 0, 0, 0);
    }
    #pragma unroll
    for (int fm = 0; fm < 2; fm++)
        #pragma unroll
        for (int fn = 0; fn < 4; fn++) {
            int col = col0 + wn * 64 + fn * 16 + l15;
            float bv = bias[col];
            #pragma unroll
            for (int r = 0; r < 4; r++) {
                int row = row0 + wm * 32 + fm * 16 + lg * 4 + r;
                float v = acc[fm][fn][r] + bv;
                if (RELU) v = fmaxf(v, 0.f);
                if (OUTBF) ((unsigned short*)Cout)[(size_t)row * 256 + col] = f2bf(v);
                else       ((float*)Cout)[(size_t)row * 256 + col] = v;
            }
        }
}

// ---------------- attention helpers
static __device__ __forceinline__ float dot32(const float* qr, const float* kv) {
    float s = 0.f;
    #pragma unroll
    for (int d4 = 0; d4 < 8; d4++) {
        float4 k4 = *(const float4*)(kv + d4 * 4);
        s += qr[d4*4+0]*k4.x + qr[d4*4+1]*k4.y + qr[d4*4+2]*k4.z + qr[d4*4+3]*k4.w;
    }
    return s;
}

static __device__ __forceinline__ void stage_eter(
    float* sET, float* sER, const float* __restrict__ rel,
    const float* __restrict__ tsp, int t, int b, int q0, int k0)
{
    #pragma unroll
    for (int j = 0; j < 4; j++) {
        int c = j * 256 + t;
        int rr = c >> 5, cc = c & 31;
        size_t gi = ((size_t)(b * SEQ + q0 + rr)) * SEQ + (k0 + cc);
        bool va = (k0 + cc) <= (q0 + rr);
        float tv = tsp[gi];
        float rv = rel[gi];
        // time numerator: exp(exp(-|t|)); rel numerator: exp(rel), 0 where masked
        sET[rr * 33 + cc] = va ? __expf(__expf(-fabsf(tv))) : 0.f;
        sER[rr * 33 + cc] = (va && rv != 0.f) ? __expf(rv) : 0.f;
    }
}

// ---------------- fused attention: thread (q,h); two-pass online softmax
__global__ __launch_bounds__(256, 2) void attn_kernel(
    const float* __restrict__ Qf,
    const float* __restrict__ Kf,
    const float* __restrict__ Vf,
    const float* __restrict__ rel,
    const float* __restrict__ tsp,
    const float* __restrict__ Wout,
    const float* __restrict__ bout,
    const float* __restrict__ pl1,
    const float* __restrict__ pl2,
    float* __restrict__ logits,
    float* __restrict__ attn)
{
    __shared__ float sK[32 * 256];
    __shared__ float sV[32 * 256];
    __shared__ float sET[32 * 33];
    __shared__ float sER[32 * 33];
    __shared__ float slog[32][9];

    const int t = threadIdx.x;
    const int qt = 15 - blockIdx.x;      // heavy tiles dispatched first
    const int b = blockIdx.y;
    const int q = t & 31;
    const int h = t >> 5;
    const int q0 = qt * 32;
    const int qg = q0 + q;

    const float l1 = pl1[0], l2 = pl2[0];
    const float cp  = (1.f - l1) * (1.f - l2);
    const float ctt = (1.f - l1) * l2;
    const float crr = l1;

    float qr[32];
    {
        const float* qp = Qf + ((size_t)(b * SEQ + qg)) * EMB + h * HD;
        #pragma unroll
        for (int i = 0; i < 8; i++) {
            float4 v = *(const float4*)(qp + i * 4);
            qr[i*4+0] = v.x * 0.17677669529663687f;   // fold 1/sqrt(32)
            qr[i*4+1] = v.y * 0.17677669529663687f;
            qr[i*4+2] = v.z * 0.17677669529663687f;
            qr[i*4+3] = v.w * 0.17677669529663687f;
        }
    }

    float m = -1e30f, denp = 0.f, dent = 0.f, denr = 0.f;

    // ---------- pass 1: denominators ----------
    for (int kt = 0; kt <= qt; kt++) {
        const int k0 = kt * 32;
        __syncthreads();
        #pragma unroll
        for (int j = 0; j < 8; j++) {
            int c = j * 256 + t;
            int kr = c >> 6, c4 = c & 63;
            *(float4*)(sK + kr * 256 + c4 * 4) =
                *(const float4*)(Kf + ((size_t)(b * SEQ + k0 + kr)) * EMB + c4 * 4);
        }
        stage_eter(sET, sER, rel, tsp, t, b, q0, k0);
        __syncthreads();
        #pragma unroll
        for (int k = 0; k < 32; k++) {
            dent += sET[q * 33 + k];
            denr += sER[q * 33 + k];
        }
        const float* kb = sK + h * HD;
        #pragma unroll
        for (int kc = 0; kc < 4; kc++) {
            float s8[8];
            #pragma unroll
            for (int kk = 0; kk < 8; kk++)
                s8[kk] = dot32(qr, kb + (kc * 8 + kk) * 256);
            float tm = -1e30f;
            #pragma unroll
            for (int kk = 0; kk < 8; kk++)
                tm = (k0 + kc * 8 + kk <= qg) ? fmaxf(tm, s8[kk]) : tm;
            float mn = fmaxf(m, tm);
            denp *= __expf(m - mn);
            #pragma unroll
            for (int kk = 0; kk < 8; kk++) {
                float e = __expf(s8[kk] - mn);
                denp += (k0 + kc * 8 + kk <= qg) ? e : 0.f;
            }
            m = mn;
        }
    }

    const float invp = 1.f / denp;
    const float invt = 1.f / dent;
    const float invr = denr > 0.f ? 1.f / denr : 0.f;

    float outacc[32];
    #pragma unroll
    for (int i = 0; i < 32; i++) outacc[i] = 0.f;

    float* arow = attn + (((size_t)(b * NHEAD + h) * SEQ) + qg) * SEQ;

    // ---------- pass 2: blend, write attn, accumulate PV ----------
    for (int kt = 0; kt <= qt; kt++) {
        const int k0 = kt * 32;
        __syncthreads();
        #pragma unroll
        for (int j = 0; j < 8; j++) {
            int c = j * 256 + t;
            int kr = c >> 6, c4 = c & 63;
            size_t src = ((size_t)(b * SEQ + k0 + kr)) * EMB + c4 * 4;
            *(float4*)(sK + kr * 256 + c4 * 4) = *(const float4*)(Kf + src);
            *(float4*)(sV + kr * 256 + c4 * 4) = *(const float4*)(Vf + src);
        }
        stage_eter(sET, sER, rel, tsp, t, b, q0, k0);
        __syncthreads();
        const float* kb = sK + h * HD;
        const float* vb = sV + h * HD;
        #pragma unroll
        for (int kc = 0; kc < 4; kc++) {
            float a8[8];
            #pragma unroll
            for (int kk = 0; kk < 8; kk++) {
                int k = kc * 8 + kk;
                float s = dot32(qr, kb + k * 256);
                float p = (k0 + k <= qg) ? __expf(s - m) * invp : 0.f;
                a8[kk] = cp * p + ctt * sET[q * 33 + k] * invt
                                + crr * sER[q * 33 + k] * invr;
            }
            *(float4*)(arow + k0 + kc * 8)     = make_float4(a8[0], a8[1], a8[2], a8[3]);
            *(float4*)(arow + k0 + kc * 8 + 4) = make_float4(a8[4], a8[5], a8[6], a8[7]);
            #pragma unroll
            for (int kk = 0; kk < 8; kk++) {
                const float* vv = vb + (kc * 8 + kk) * 256;
                float av = a8[kk];
                #pragma unroll
                for (int d4 = 0; d4 < 8; d4++) {
                    float4 v4 = *(const float4*)(vv + d4 * 4);
                    outacc[d4*4+0] += av * v4.x;
                    outacc[d4*4+1] += av * v4.y;
                    outacc[d4*4+2] += av * v4.z;
                    outacc[d4*4+3] += av * v4.w;
                }
            }
        }
    }

    // ---------- zero-fill strictly-future tiles ----------
    for (int kt = qt + 1; kt < 16; kt++) {
        const int k0 = kt * 32;
        #pragma unroll
        for (int j = 0; j < 8; j++) {
            int c = j * 256 + t;
            int hh = c >> 8, rem = c & 255;
            int qq = rem >> 3, ch = rem & 7;
            *(float4*)(attn + (((size_t)(b * NHEAD + hh) * SEQ) + q0 + qq) * SEQ
                       + k0 + ch * 4) = make_float4(0.f, 0.f, 0.f, 0.f);
        }
    }

    // ---------- logits = out . W_out + b_out ----------
    float part = 0.f;
    #pragma unroll
    for (int d = 0; d < 32; d++) part += outacc[d] * Wout[h * HD + d];
    slog[q][h] = part;
    __syncthreads();
    if (t < 32) {
        float sum = bout[0];
        #pragma unroll
        for (int hh = 0; hh < 8; hh++) sum += slog[t][hh];
        logits[b * SEQ + q0 + t] = sum;
    }
}

// ---------------- host launch ----------------
extern "C" void kernel_launch(void* const* d_in, const int* in_sizes, int n_in,
                              void* d_out, int out_size, void* d_ws, size_t ws_size,
                              hipStream_t stream)
{
    (void)in_sizes; (void)n_in; (void)out_size; (void)ws_size;
    const int*   item_inputs  = (const int*)d_in[0];
    const int*   label_inputs = (const int*)d_in[1];
    const int*   item_ids     = (const int*)d_in[2];
    const float* rel   = (const float*)d_in[3];
    const float* tsp   = (const float*)d_in[4];
    const float* emb   = (const float*)d_in[5];
    const float* W_in  = (const float*)d_in[6];
    const float* b_in  = (const float*)d_in[7];
    const float* Wq    = (const float*)d_in[8];
    const float* bq    = (const float*)d_in[9];
    const float* Wk    = (const float*)d_in[10];
    const float* bk    = (const float*)d_in[11];
    const float* Wv    = (const float*)d_in[12];
    const float* bv    = (const float*)d_in[13];
    const float* Wout  = (const float*)d_in[14];
    const float* bout  = (const float*)d_in[15];
    const float* l1    = (const float*)d_in[16];
    const float* l2    = (const float*)d_in[17];

    const size_t R = 16384;
    char* w = (char*)d_ws;
    unsigned short* Abig = (unsigned short*)w; w += R * 512 * 2;
    unsigned short* qbf  = (unsigned short*)w; w += R * 256 * 2;
    unsigned short* WTin = (unsigned short*)w; w += (size_t)256 * 512 * 2;
    unsigned short* WTq  = (unsigned short*)w; w += (size_t)256 * 256 * 2;
    unsigned short* WTk  = (unsigned short*)w; w += (size_t)256 * 256 * 2;
    unsigned short* WTv  = (unsigned short*)w; w += (size_t)256 * 256 * 2;
    unsigned short* Xbf  = (unsigned short*)w; w += R * 256 * 2;
    float* Qf = (float*)w; w += R * 256 * 4;
    float* Kf = (float*)w; w += R * 256 * 4;
    float* Vf = (float*)w; w += R * 256 * 4;
    // total workspace use: ~84.4 MB

    prep_kernel<<<dim3(8192), dim3(256), 0, stream>>>(
        item_inputs, label_inputs, item_ids, emb, Abig, qbf);
    wtrans_kernel<<<dim3(512), dim3(256), 0, stream>>>(W_in, WTin, 512, 256);
    wtrans_kernel<<<dim3(256), dim3(256), 0, stream>>>(Wq, WTq, 256, 256);
    wtrans_kernel<<<dim3(256), dim3(256), 0, stream>>>(Wk, WTk, 256, 256);
    wtrans_kernel<<<dim3(256), dim3(256), 0, stream>>>(Wv, WTv, 256, 256);

    gemm_kernel<512,1,1><<<dim3(256,2), dim3(256), 0, stream>>>(Abig, WTin, b_in, (void*)Xbf);
    gemm_kernel<256,0,0><<<dim3(256,2), dim3(256), 0, stream>>>(qbf,  WTq,  bq,  (void*)Qf);
    gemm_kernel<256,0,0><<<dim3(256,2), dim3(256), 0, stream>>>(Xbf,  WTk,  bk,  (void*)Kf);
    gemm_kernel<256,0,0><<<dim3(256,2), dim3(256), 0, stream>>>(Xbf,  WTv,  bv,  (void*)Vf);

    float* logits = (float*)d_out;
    float* attnp  = (float*)d_out + 16384;
    attn_kernel<<<dim3(16, 32), dim3(256), 0, stream>>>(
        Qf, Kf, Vf, rel, tsp, Wout, bout, l1, l2, logits, attnp);
}

// Round 2
// 209.595 us; speedup vs baseline: 2.3988x; 2.3988x over previous
//
#include <hip/hip_runtime.h>
#include <hip/hip_bf16.h>

#define SEQ 512
#define EMB 256
#define NHEAD 8
#define HD 32

using bf16x8 = __attribute__((ext_vector_type(8))) short;
using f32x4  = __attribute__((ext_vector_type(4))) float;

static __device__ __forceinline__ unsigned short f2bf(float x) {
    union { float f; unsigned int u; } v; v.f = x;
    unsigned int r = v.u + 0x7FFFu + ((v.u >> 16) & 1u);
    return (unsigned short)(r >> 16);
}
static __device__ __forceinline__ float bf2f(unsigned short v) {
    union { unsigned int u; float f; } w; w.u = ((unsigned int)v) << 16; return w.f;
}

// ---------------- prep: gather embeds, build masked-concat A (bf16) + query (bf16)
__global__ __launch_bounds__(256) void prep_kernel(
    const int* __restrict__ item_inputs,
    const int* __restrict__ label_inputs,
    const int* __restrict__ item_ids,
    const float* __restrict__ embeds,
    unsigned short* __restrict__ Abig,   // 16384 x 512 bf16
    unsigned short* __restrict__ qbf)    // 16384 x 256 bf16
{
    int t = threadIdx.x;
    int r = blockIdx.x * 2 + (t >> 7);
    int j = (t & 127) * 2;
    int item = item_inputs[r];
    int lab  = label_inputs[r];
    int qid  = item_ids[r];
    float2 e2 = *(const float2*)(embeds + (size_t)item * EMB + j);
    ushort2 on  = make_ushort2(f2bf(e2.x), f2bf(e2.y));
    ushort2 off = make_ushort2(0, 0);
    *(ushort2*)(Abig + (size_t)r * 512 + j)       = lab ? on : off;
    *(ushort2*)(Abig + (size_t)r * 512 + 256 + j) = lab ? off : on;
    float2 q2 = *(const float2*)(embeds + (size_t)qid * EMB + j);
    *(ushort2*)(qbf + (size_t)r * 256 + j) = make_ushort2(f2bf(q2.x), f2bf(q2.y));
}

// ---------------- weight transpose + bf16 convert: W (K x N) -> WT (N x K)
__global__ void wtrans_kernel(const float* __restrict__ W,
                              unsigned short* __restrict__ WT,
                              int K, int N)
{
    int idx = blockIdx.x * 256 + threadIdx.x;
    if (idx >= K * N) return;
    int n = idx / K, k = idx - n * K;
    WT[idx] = f2bf(W[(size_t)k * N + n]);
}

// ---------------- Wvw[c][h] = sum_d Wv[c][32h+d]*Wout[32h+d]; bvw[h] likewise from bv
__global__ void wvw_kernel(const float* __restrict__ Wv,
                           const float* __restrict__ Wout,
                           const float* __restrict__ bv,
                           float* __restrict__ Wvw,
                           float* __restrict__ bvw)
{
    int idx = blockIdx.x * 256 + threadIdx.x;  // grid 8 -> 2048
    int c = idx >> 3, h = idx & 7;
    float s = 0.f;
    #pragma unroll
    for (int d = 0; d < 32; d++) s += Wv[(size_t)c * 256 + h * 32 + d] * Wout[h * 32 + d];
    Wvw[idx] = s;
    if (idx < 8) {
        float s2 = 0.f;
        #pragma unroll
        for (int d = 0; d < 32; d++) s2 += bv[idx * 32 + d] * Wout[idx * 32 + d];
        bvw[idx] = s2;
    }
}

// ---------------- Vw[row][h] = X[row]·Wvw[:,h] + bvw[h]
__global__ __launch_bounds__(256) void vw_kernel(
    const unsigned short* __restrict__ Xbf,
    const float* __restrict__ Wvw,
    const float* __restrict__ bvw,
    float* __restrict__ Vw)
{
    __shared__ float sW[2048];
    __shared__ float sb[8];
    int t = threadIdx.x;
    #pragma unroll
    for (int i = 0; i < 8; i++) sW[i * 256 + t] = Wvw[i * 256 + t];
    if (t < 8) sb[t] = bvw[t];
    __syncthreads();
    int row = blockIdx.x * 256 + t;
    float acc[8];
    #pragma unroll
    for (int h = 0; h < 8; h++) acc[h] = sb[h];
    for (int d0 = 0; d0 < 32; d0++) {
        bf16x8 x = *(const bf16x8*)(Xbf + (size_t)row * 256 + d0 * 8);
        #pragma unroll
        for (int j = 0; j < 8; j++) {
            float xf = bf2f((unsigned short)x[j]);
            #pragma unroll
            for (int h = 0; h < 8; h++) acc[h] += xf * sW[(d0 * 8 + j) * 8 + h];
        }
    }
    *(float4*)(Vw + (size_t)row * 8)     = make_float4(acc[0], acc[1], acc[2], acc[3]);
    *(float4*)(Vw + (size_t)row * 8 + 4) = make_float4(acc[4], acc[5], acc[6], acc[7]);
}

// ---------------- MFMA GEMM: C(M x 256) = A(M x KDIM) * WT^T + bias, opt relu, scale
template<int KDIM, int RELU, int OUTBF>
__global__ __launch_bounds__(256, 2) void gemm_kernel(
    const unsigned short* __restrict__ A,
    const unsigned short* __restrict__ BT,   // 256 x KDIM (pre-transposed)
    const float* __restrict__ bias,
    void* __restrict__ Cout, float scale)
{
    __shared__ unsigned short As[64][40];
    __shared__ unsigned short Bs[128][40];
    const int t = threadIdx.x;
    const int row0 = blockIdx.x * 64;
    const int col0 = blockIdx.y * 128;
    const int wid = t >> 6, lane = t & 63;
    const int wm = wid & 1, wn = wid >> 1;
    const int lg = lane >> 4, l15 = lane & 15;

    f32x4 acc[2][4];
    #pragma unroll
    for (int i = 0; i < 2; i++)
        #pragma unroll
        for (int j = 0; j < 4; j++) acc[i][j] = (f32x4){0.f, 0.f, 0.f, 0.f};

    const int arow = t >> 2, achk = t & 3;
    const int brow = t >> 1, bhalf = t & 1;

    for (int k0 = 0; k0 < KDIM; k0 += 32) {
        __syncthreads();
        *(uint4*)(&As[arow][achk * 8]) =
            *(const uint4*)(A + (size_t)(row0 + arow) * KDIM + k0 + achk * 8);
        const unsigned short* bsrc = BT + (size_t)(col0 + brow) * KDIM + k0 + bhalf * 16;
        *(uint4*)(&Bs[brow][bhalf * 16])     = *(const uint4*)(bsrc);
        *(uint4*)(&Bs[brow][bhalf * 16 + 8]) = *(const uint4*)(bsrc + 8);
        __syncthreads();
        bf16x8 af[2], bfr[4];
        #pragma unroll
        for (int fm = 0; fm < 2; fm++)
            af[fm] = *(const bf16x8*)(&As[wm * 32 + fm * 16 + l15][lg * 8]);
        #pragma unroll
        for (int fn = 0; fn < 4; fn++)
            bfr[fn] = *(const bf16x8*)(&Bs[wn * 64 + fn * 16 + l15][lg * 8]);
        #pragma unroll
        for (int fm = 0; fm < 2; fm++)
            #pragma unroll
            for (int fn = 0; fn < 4; fn++)
                acc[fm][fn] = __builtin_amdgcn_mfma_f32_16x16x32_bf16(
                    af[fm], bfr[fn], acc[fm][fn], 0, 0, 0);
    }
    #pragma unroll
    for (int fm = 0; fm < 2; fm++)
        #pragma unroll
        for (int fn = 0; fn < 4; fn++) {
            int col = col0 + wn * 64 + fn * 16 + l15;
            float bv = bias[col];
            #pragma unroll
            for (int r = 0; r < 4; r++) {
                int row = row0 + wm * 32 + fm * 16 + lg * 4 + r;
                float v = acc[fm][fn][r] + bv;
                if (RELU) v = fmaxf(v, 0.f);
                v *= scale;
                if (OUTBF) ((unsigned short*)Cout)[(size_t)row * 256 + col] = f2bf(v);
                else       ((float*)Cout)[(size_t)row * 256 + col] = v;
            }
        }
}

// ---------------- fused attention v2: MFMA scores, in-reg softmax stats, Vw logits
__global__ __launch_bounds__(256, 3) void attn2_kernel(
    const unsigned short* __restrict__ Qbf,
    const unsigned short* __restrict__ Kbf,
    const float* __restrict__ Vw,
    const float* __restrict__ rel,
    const float* __restrict__ tsp,
    const float* __restrict__ bout,
    const float* __restrict__ pl1,
    const float* __restrict__ pl2,
    float* __restrict__ logits,
    float* __restrict__ attn)
{
    __shared__ float sET[32 * 33];
    __shared__ float sER[32 * 33];
    __shared__ float sVwT[8][512];
    __shared__ float sinvt[32];
    __shared__ float sinvr[32];
    __shared__ float slog[4][32];

    const int t = threadIdx.x;
    const int qt = 15 - blockIdx.x;          // heavy tiles first
    const int b  = blockIdx.y;
    const int q0 = qt * 32;
    const int w    = t >> 6;
    const int lane = t & 63;
    const int l15  = lane & 15;
    const int lg   = lane >> 4;

    const float l1 = pl1[0], l2 = pl2[0];
    const float cp = (1.f - l1) * (1.f - l2);
    const float ct = (1.f - l1) * l2;
    const float cr = l1;

    // Q fragments: rows q0+mf*16+l15, dims h*32 + lg*8..+7 (A frag of 16x16x32)
    bf16x8 aq[2][2];
    #pragma unroll
    for (int hh = 0; hh < 2; hh++)
        #pragma unroll
        for (int mf = 0; mf < 2; mf++)
            aq[hh][mf] = *(const bf16x8*)(Qbf +
                (size_t)(b * SEQ + q0 + mf * 16 + l15) * EMB + (2 * w + hh) * 32 + lg * 8);

    // stage Vw transposed: sVwT[h][k]
    #pragma unroll
    for (int i = 0; i < 16; i++) {
        int idx = i * 256 + t;
        sVwT[idx & 7][idx >> 3] = Vw[(size_t)b * (SEQ * 8) + idx];
    }

    // ---------- pass 1: denp per (head,row) in regs; dent/denr streamed ----------
    const int rr  = t >> 3;           // rel/ts row 0..31
    const int cc4 = (t & 7) * 4;      // col group
    const int qrow_s = q0 + rr;
    float dtp = 0.f, drp = 0.f;
    f32x4 dacc[2][2];
    #pragma unroll
    for (int hh = 0; hh < 2; hh++)
        #pragma unroll
        for (int mf = 0; mf < 2; mf++) dacc[hh][mf] = (f32x4){0.f, 0.f, 0.f, 0.f};

    for (int kt = 0; kt <= qt; kt++) {
        const int k0 = kt * 32;
        size_t gi = ((size_t)(b * SEQ) + qrow_s) * SEQ + k0 + cc4;
        float4 tv4 = *(const float4*)(tsp + gi);
        float4 rv4 = *(const float4*)(rel + gi);
        const float* tvp = &tv4.x;
        const float* rvp = &rv4.x;
        #pragma unroll
        for (int j = 0; j < 4; j++) {
            bool va = (k0 + cc4 + j) <= qrow_s;
            dtp += va ? __expf(__expf(-fabsf(tvp[j]))) : 0.f;
            drp += (va && rvp[j] != 0.f) ? __expf(rvp[j]) : 0.f;
        }
        #pragma unroll
        for (int hh = 0; hh < 2; hh++) {
            const int h = 2 * w + hh;
            #pragma unroll
            for (int nf = 0; nf < 2; nf++) {
                bf16x8 bk = *(const bf16x8*)(Kbf +
                    (size_t)(b * SEQ + k0 + nf * 16 + l15) * EMB + h * 32 + lg * 8);
                const int kcol = k0 + nf * 16 + l15;
                #pragma unroll
                for (int mf = 0; mf < 2; mf++) {
                    f32x4 acc = __builtin_amdgcn_mfma_f32_16x16x32_bf16(
                        aq[hh][mf], bk, (f32x4){0.f, 0.f, 0.f, 0.f}, 0, 0, 0);
                    #pragma unroll
                    for (int r = 0; r < 4; r++) {
                        int qrow = q0 + mf * 16 + lg * 4 + r;
                        float e = (kcol <= qrow) ? __expf(acc[r]) : 0.f;
                        dacc[hh][mf][r] += e;
                    }
                }
            }
        }
    }

    // reduce dent/denr across the 8 col-threads of each row
    #pragma unroll
    for (int m = 1; m < 8; m <<= 1) {
        dtp += __shfl_xor(dtp, m);
        drp += __shfl_xor(drp, m);
    }
    if ((t & 7) == 0) {
        sinvt[rr] = 1.f / dtp;
        sinvr[rr] = drp > 0.f ? 1.f / drp : 0.f;
    }

    // butterfly-reduce denp over the 16 key-lanes -> every lane has its rows' inv
    float invp[2][2][4];
    #pragma unroll
    for (int hh = 0; hh < 2; hh++)
        #pragma unroll
        for (int mf = 0; mf < 2; mf++)
            #pragma unroll
            for (int r = 0; r < 4; r++) {
                float v = dacc[hh][mf][r];
                v += __shfl_xor(v, 1);
                v += __shfl_xor(v, 2);
                v += __shfl_xor(v, 4);
                v += __shfl_xor(v, 8);
                invp[hh][mf][r] = 1.f / v;
            }
    __syncthreads();   // sinvt/sinvr visible

    // ---------- pass 2: recompute scores, blend, write attn, accumulate logits ----------
    float plog[2][4] = {{0.f,0.f,0.f,0.f},{0.f,0.f,0.f,0.f}};

    for (int kt = 0; kt <= qt; kt++) {
        const int k0 = kt * 32;
        __syncthreads();
        {   // stage ET/ER numerators (shared by all heads)
            size_t gi = ((size_t)(b * SEQ) + qrow_s) * SEQ + k0 + cc4;
            float4 tv4 = *(const float4*)(tsp + gi);
            float4 rv4 = *(const float4*)(rel + gi);
            const float* tvp = &tv4.x;
            const float* rvp = &rv4.x;
            #pragma unroll
            for (int j = 0; j < 4; j++) {
                bool va = (k0 + cc4 + j) <= qrow_s;
                sET[rr * 33 + cc4 + j] = va ? __expf(__expf(-fabsf(tvp[j]))) : 0.f;
                sER[rr * 33 + cc4 + j] = (va && rvp[j] != 0.f) ? __expf(rvp[j]) : 0.f;
            }
        }
        __syncthreads();
        #pragma unroll
        for (int hh = 0; hh < 2; hh++) {
            const int h = 2 * w + hh;
            #pragma unroll
            for (int nf = 0; nf < 2; nf++) {
                bf16x8 bk = *(const bf16x8*)(Kbf +
                    (size_t)(b * SEQ + k0 + nf * 16 + l15) * EMB + h * 32 + lg * 8);
                const int kcol = k0 + nf * 16 + l15;
                const int kloc = nf * 16 + l15;
                const float vw = sVwT[h][kcol];
                #pragma unroll
                for (int mf = 0; mf < 2; mf++) {
                    f32x4 acc = __builtin_amdgcn_mfma_f32_16x16x32_bf16(
                        aq[hh][mf], bk, (f32x4){0.f, 0.f, 0.f, 0.f}, 0, 0, 0);
                    #pragma unroll
                    for (int r = 0; r < 4; r++) {
                        int qloc = mf * 16 + lg * 4 + r;
                        int qrow = q0 + qloc;
                        float a = 0.f;
                        if (kcol <= qrow) {
                            float p = __expf(acc[r]) * invp[hh][mf][r];
                            a = cp * p + ct * sET[qloc * 33 + kloc] * sinvt[qloc]
                                       + cr * sER[qloc * 33 + kloc] * sinvr[qloc];
                        }
                        attn[((size_t)((b * NHEAD + h) * SEQ) + qrow) * SEQ + kcol] = a;
                        plog[mf][r] += a * vw;
                    }
                }
            }
        }
    }

    // ---------- zero-fill strictly-future tiles ----------
    {
        const int zrow = t >> 3, zc4 = (t & 7) * 4;
        for (int kt = qt + 1; kt < 16; kt++) {
            const int k0 = kt * 32;
            #pragma unroll
            for (int h = 0; h < NHEAD; h++)
                *(float4*)(attn + ((size_t)((b * NHEAD + h) * SEQ) + q0 + zrow) * SEQ
                           + k0 + zc4) = make_float4(0.f, 0.f, 0.f, 0.f);
        }
    }

    // ---------- logits ----------
    #pragma unroll
    for (int mf = 0; mf < 2; mf++)
        #pragma unroll
        for (int r = 0; r < 4; r++) {
            float v = plog[mf][r];
            v += __shfl_xor(v, 1);
            v += __shfl_xor(v, 2);
            v += __shfl_xor(v, 4);
            v += __shfl_xor(v, 8);
            if (l15 == 0) slog[w][mf * 16 + lg * 4 + r] = v;
        }
    __syncthreads();
    if (t < 32)
        logits[b * SEQ + q0 + t] = bout[0] + slog[0][t] + slog[1][t] + slog[2][t] + slog[3][t];
}

// ---------------- host launch ----------------
extern "C" void kernel_launch(void* const* d_in, const int* in_sizes, int n_in,
                              void* d_out, int out_size, void* d_ws, size_t ws_size,
                              hipStream_t stream)
{
    (void)in_sizes; (void)n_in; (void)out_size; (void)ws_size;
    const int*   item_inputs  = (const int*)d_in[0];
    const int*   label_inputs = (const int*)d_in[1];
    const int*   item_ids     = (const int*)d_in[2];
    const float* rel   = (const float*)d_in[3];
    const float* tsp   = (const float*)d_in[4];
    const float* emb   = (const float*)d_in[5];
    const float* W_in  = (const float*)d_in[6];
    const float* b_in  = (const float*)d_in[7];
    const float* Wq    = (const float*)d_in[8];
    const float* bq    = (const float*)d_in[9];
    const float* Wk    = (const float*)d_in[10];
    const float* bk    = (const float*)d_in[11];
    const float* Wv    = (const float*)d_in[12];
    const float* bv    = (const float*)d_in[13];
    const float* Wout  = (const float*)d_in[14];
    const float* bout  = (const float*)d_in[15];
    const float* l1    = (const float*)d_in[16];
    const float* l2    = (const float*)d_in[17];

    const size_t R = 16384;
    char* w = (char*)d_ws;
    unsigned short* Abig = (unsigned short*)w; w += R * 512 * 2;
    unsigned short* qbf  = (unsigned short*)w; w += R * 256 * 2;
    unsigned short* WTin = (unsigned short*)w; w += (size_t)256 * 512 * 2;
    unsigned short* WTq  = (unsigned short*)w; w += (size_t)256 * 256 * 2;
    unsigned short* WTk  = (unsigned short*)w; w += (size_t)256 * 256 * 2;
    unsigned short* Xbf  = (unsigned short*)w; w += R * 256 * 2;
    unsigned short* Qbf  = (unsigned short*)w; w += R * 256 * 2;
    unsigned short* Kbf  = (unsigned short*)w; w += R * 256 * 2;
    float* Wvw = (float*)w; w += 2048 * 4;
    float* Vw  = (float*)w; w += R * 8 * 4;
    float* bvw = (float*)w; w += 256;
    // total ~52 MB

    prep_kernel<<<dim3(8192), dim3(256), 0, stream>>>(
        item_inputs, label_inputs, item_ids, emb, Abig, qbf);
    wtrans_kernel<<<dim3(512), dim3(256), 0, stream>>>(W_in, WTin, 512, 256);
    wtrans_kernel<<<dim3(256), dim3(256), 0, stream>>>(Wq, WTq, 256, 256);
    wtrans_kernel<<<dim3(256), dim3(256), 0, stream>>>(Wk, WTk, 256, 256);
    wvw_kernel<<<dim3(8), dim3(256), 0, stream>>>(Wv, Wout, bv, Wvw, bvw);

    gemm_kernel<512,1,1><<<dim3(256,2), dim3(256), 0, stream>>>(Abig, WTin, b_in, (void*)Xbf, 1.0f);
    gemm_kernel<256,0,1><<<dim3(256,2), dim3(256), 0, stream>>>(qbf,  WTq,  bq,  (void*)Qbf, 0.17677669529663687f);
    gemm_kernel<256,0,1><<<dim3(256,2), dim3(256), 0, stream>>>(Xbf,  WTk,  bk,  (void*)Kbf, 1.0f);
    vw_kernel<<<dim3(64), dim3(256), 0, stream>>>(Xbf, Wvw, bvw, Vw);

    float* logits = (float*)d_out;
    float* attnp  = (float*)d_out + 16384;
    attn2_kernel<<<dim3(16, 32), dim3(256), 0, stream>>>(
        Qbf, Kbf, Vw, rel, tsp, bout, l1, l2, logits, attnp);
}